// Round 3
// baseline (182.792 us; speedup 1.0000x reference)
//
#include <hip/hip_runtime.h>

// R10: revert to ROWS=2 champion (R7, 54.2us) + overhead trims.
// R9 post-mortem: ROWS=1 spill-free at 2x waves ran 61.5us with LOWER
// VALUBusy (60 vs 66) and equal total busy cycles -> NOT latency-bound at
// 4 waves/SIMD; occupancy lever is dead. ROWS=2's in-wave ILP + amortized
// per-wave uniform work wins. Symmetric-attn1 exp cut is register-infeasible
// (136-entry triangle -> 272 VGPR at ROWS=2).
// This round targets the ~35% gap between measured busy (21.4k cy/wave) and
// static algorithmic issue (13.8k): (1) masked-load machinery replaced by
// clamped-index loads + masked store only; (2) MLP uniform weight loads all
// hoisted to group-body top + unroll 4 (batch s_load issue, amortize
// lgkmcnt waits 2x vs unroll 2); (3) v1 deferred out of attn1 inner loop.
// Tripwire: WRITE_SIZE must stay 2048 (no spill).
// Kept: s_load weight path (no LDS, no barrier), exp2-domain softmax/sigmoid
// with per-row attained-max shift, Montgomery-batched sigmoid rcps, packed
// fp32 (v_pk_fma_f32), tree sums, x loads issued first.

typedef float v2f __attribute__((ext_vector_type(2)));

#define LOG2E 1.44269504088896340736f
#define ROWS 2

__device__ __forceinline__ float rcpf(float a) { return __builtin_amdgcn_rcpf(a); }

#if __has_builtin(__builtin_amdgcn_exp2f)
__device__ __forceinline__ float exp2_fast(float a) { return __builtin_amdgcn_exp2f(a); }
#else
__device__ __forceinline__ float exp2_fast(float a) { return __expf(0.6931471805599453f * a); }
#endif

__global__ __launch_bounds__(256, 4) void fused_attn_mlp(
    const float* __restrict__ x,
    const float* __restrict__ wq,
    const float* __restrict__ wk,
    const float* __restrict__ wv,
    const float* __restrict__ Wh,
    const float* __restrict__ bh,
    const float* __restrict__ Wo,
    const float* __restrict__ bo,
    float* __restrict__ out,
    int B)
{
    const int t = threadIdx.x;
    const int b0 = blockIdx.x * (256 * ROWS) + t;

    // Clamped indices: loads always in-bounds, no exec-mask load machinery.
    // Stores masked by valid[]. Correct for any B.
    bool valid[ROWS];
    int bidx[ROWS];
    #pragma unroll
    for (int r = 0; r < ROWS; ++r) {
        const int b = b0 + r * 256;
        valid[r] = b < B;
        bidx[r] = valid[r] ? b : (B - 1);
    }

    // ---- issue x loads first (VMEM latency hides under s_load setup) ----
    float4 xraw[ROWS][4];
    #pragma unroll
    for (int r = 0; r < ROWS; ++r) {
        const float4* xr = reinterpret_cast<const float4*>(x) + (size_t)bidx[r] * 4;
        xraw[r][0] = xr[0]; xraw[r][1] = xr[1]; xraw[r][2] = xr[2]; xraw[r][3] = xr[3];
    }

    // ---- unpack x rows ----
    float xs[ROWS][16];
    v2f xv2[ROWS][8];
    #pragma unroll
    for (int r = 0; r < ROWS; ++r) {
        xs[r][0]=xraw[r][0].x; xs[r][1]=xraw[r][0].y; xs[r][2]=xraw[r][0].z; xs[r][3]=xraw[r][0].w;
        xs[r][4]=xraw[r][1].x; xs[r][5]=xraw[r][1].y; xs[r][6]=xraw[r][1].z; xs[r][7]=xraw[r][1].w;
        xs[r][8]=xraw[r][2].x; xs[r][9]=xraw[r][2].y; xs[r][10]=xraw[r][2].z; xs[r][11]=xraw[r][2].w;
        xs[r][12]=xraw[r][3].x; xs[r][13]=xraw[r][3].y; xs[r][14]=xraw[r][3].z; xs[r][15]=xraw[r][3].w;
        #pragma unroll
        for (int p = 0; p < 8; ++p) { v2f v; v[0]=xs[r][2*p]; v[1]=xs[r][2*p+1]; xv2[r][p]=v; }
    }

    // ---- attention block 1 (D=16), exp2 domain ----
    const float kq1 = wk[0] * wq[0] * LOG2E;
    const float v1  = wv[0];

    float xmx[ROWS], xmn[ROWS];
    #pragma unroll
    for (int r = 0; r < ROWS; ++r) {
        float mx = xs[r][0], mn = xs[r][0];
        #pragma unroll
        for (int i = 1; i < 16; ++i) { mx = fmaxf(mx, xs[r][i]); mn = fminf(mn, xs[r][i]); }
        xmx[r] = mx; xmn[r] = mn;
    }

    v2f o1v[ROWS][8];
    #pragma unroll
    for (int r = 0; r < ROWS; ++r)
        #pragma unroll
        for (int p = 0; p < 8; ++p) o1v[r][p] = (v2f)(0.f);

    #pragma unroll
    for (int i = 0; i < 16; ++i) {
        v2f e2[ROWS][8];
        float w[ROWS];
        #pragma unroll
        for (int r = 0; r < ROWS; ++r) {
            const float c = kq1 * xs[r][i];
            const float m = fmaxf(c * xmx[r], c * xmn[r]);   // exact attained max -> args <= 0
            v2f cc; cc[0]=c; cc[1]=c;
            v2f mm; mm[0]=m; mm[1]=m;
            #pragma unroll
            for (int p = 0; p < 8; ++p) {
                v2f a = cc * xv2[r][p] - mm;                 // v_pk_fma_f32
                v2f e; e[0] = exp2_fast(a[0]); e[1] = exp2_fast(a[1]);
                e2[r][p] = e;
            }
            v2f s01 = e2[r][0] + e2[r][1];
            v2f s23 = e2[r][2] + e2[r][3];
            v2f s45 = e2[r][4] + e2[r][5];
            v2f s67 = e2[r][6] + e2[r][7];
            v2f sv  = (s01 + s23) + (s45 + s67);
            w[r] = xs[r][i] * rcpf(sv[0] + sv[1]);           // v1 deferred
        }
        #pragma unroll
        for (int r = 0; r < ROWS; ++r) {
            v2f ww; ww[0]=w[r]; ww[1]=w[r];
            #pragma unroll
            for (int p = 0; p < 8; ++p) o1v[r][p] += ww * e2[r][p];
        }
    }

    // deferred v1 scale (one 8-pk pass per row instead of 16 muls in-loop)
    {
        v2f v1v; v1v[0]=v1; v1v[1]=v1;
        #pragma unroll
        for (int r = 0; r < ROWS; ++r)
            #pragma unroll
            for (int p = 0; p < 8; ++p) o1v[r][p] *= v1v;
    }

    // ---- fused MLP: 16 -> 64 sigmoid -> 8. All of a group's uniform weight
    //      loads batched at body top (s_load issue groups, amortized waits). ----
    v2f x2v[ROWS][4];
    #pragma unroll
    for (int r = 0; r < ROWS; ++r)
        #pragma unroll
        for (int p = 0; p < 4; ++p) { v2f v; v[0]=bo[2*p]; v[1]=bo[2*p+1]; x2v[r][p]=v; }

    const v2f* Wh2 = reinterpret_cast<const v2f*>(Wh);   // [64][8] pairs

    #pragma unroll 4
    for (int g = 0; g < 16; ++g) {
        // ---- all uniform loads for this group first ----
        v2f whr[4][8];
        float bhh[4];
        v2f wog[4][4];   // wog[hh][p] = {Wo[2p][h], Wo[2p+1][h]}
        #pragma unroll
        for (int hh = 0; hh < 4; ++hh) {
            const int h = g * 4 + hh;
            #pragma unroll
            for (int p = 0; p < 8; ++p) whr[hh][p] = Wh2[h * 8 + p];   // uniform -> s_load
            bhh[hh] = bh[h];
            #pragma unroll
            for (int p = 0; p < 4; ++p) {
                v2f wv2; wv2[0] = Wo[(2 * p) * 64 + h]; wv2[1] = Wo[(2 * p + 1) * 64 + h];
                wog[hh][p] = wv2;
            }
        }
        // ---- hidden-layer dots ----
        float apre[ROWS][4];
        #pragma unroll
        for (int hh = 0; hh < 4; ++hh) {
            #pragma unroll
            for (int r = 0; r < ROWS; ++r) {
                v2f acc = whr[hh][0] * o1v[r][0];
                #pragma unroll
                for (int p = 1; p < 8; ++p) acc += whr[hh][p] * o1v[r][p];
                apre[r][hh] = acc[0] + acc[1] + bhh[hh];
            }
        }
        // ---- sigmoid, Montgomery-batched rcp ----
        float sg[ROWS][4];
        #pragma unroll
        for (int r = 0; r < ROWS; ++r) {
            // clamp inert for a > -20.8 (sigma < 1e-9 there); keeps
            // d = 1+2^la <= 1+2^30, so prod4 <= 2^121 (no overflow).
            float d[4];
            #pragma unroll
            for (int hh = 0; hh < 4; ++hh) {
                const float la = fminf(-apre[r][hh] * LOG2E, 30.f);
                d[hh] = 1.f + exp2_fast(la);
            }
            const float p01  = d[0] * d[1];
            const float p012 = p01 * d[2];
            const float rq   = rcpf(p012 * d[3]);
            const float i3 = rq * p012;
            const float tq = rq * d[3];      // 1/(d0 d1 d2)
            const float i2 = tq * p01;
            const float t2 = tq * d[2];      // 1/(d0 d1)
            sg[r][0] = t2 * d[1];
            sg[r][1] = t2 * d[0];
            sg[r][2] = i2;
            sg[r][3] = i3;
        }
        // ---- output-layer accumulation ----
        #pragma unroll
        for (int hh = 0; hh < 4; ++hh) {
            #pragma unroll
            for (int r = 0; r < ROWS; ++r) {
                v2f sgv; sgv[0] = sg[r][hh]; sgv[1] = sg[r][hh];
                #pragma unroll
                for (int p = 0; p < 4; ++p) {      // p = output pair (o = 2p, 2p+1)
                    x2v[r][p] += wog[hh][p] * sgv;
                }
            }
        }
    }

    // ---- attention block 2 (D=8), exp2 domain; LOG2E folded into o2 ----
    const float kq2 = wk[1] * wq[1] * LOG2E;
    const float v2s = wv[1] * LOG2E;

    float ys[ROWS][8];
    float ymx[ROWS], ymn[ROWS];
    #pragma unroll
    for (int r = 0; r < ROWS; ++r) {
        #pragma unroll
        for (int i = 0; i < 8; ++i) ys[r][i] = x2v[r][i >> 1][i & 1];
        float mx = ys[r][0], mn = ys[r][0];
        #pragma unroll
        for (int i = 1; i < 8; ++i) { mx = fmaxf(mx, ys[r][i]); mn = fminf(mn, ys[r][i]); }
        ymx[r] = mx; ymn[r] = mn;
    }

    v2f o2v[ROWS][4];
    #pragma unroll
    for (int r = 0; r < ROWS; ++r)
        #pragma unroll
        for (int p = 0; p < 4; ++p) o2v[r][p] = (v2f)(0.f);

    #pragma unroll
    for (int i = 0; i < 8; ++i) {
        v2f e2[ROWS][4];
        float w[ROWS];
        #pragma unroll
        for (int r = 0; r < ROWS; ++r) {
            const float c = kq2 * ys[r][i];
            const float m = fmaxf(c * ymx[r], c * ymn[r]);
            v2f cc; cc[0]=c; cc[1]=c;
            v2f mm; mm[0]=m; mm[1]=m;
            #pragma unroll
            for (int p = 0; p < 4; ++p) {
                v2f a = cc * x2v[r][p] - mm;
                v2f e; e[0] = exp2_fast(a[0]); e[1] = exp2_fast(a[1]);
                e2[r][p] = e;
            }
            v2f sv = (e2[r][0] + e2[r][1]) + (e2[r][2] + e2[r][3]);
            w[r] = v2s * ys[r][i] * rcpf(sv[0] + sv[1]);
        }
        #pragma unroll
        for (int r = 0; r < ROWS; ++r) {
            v2f ww; ww[0]=w[r]; ww[1]=w[r];
            #pragma unroll
            for (int p = 0; p < 4; ++p) o2v[r][p] += ww * e2[r][p];
        }
    }

    // ---- final softmax (log2 domain) + dot with x[8:16] ----
    #pragma unroll
    for (int r = 0; r < ROWS; ++r) {
        float o2s[8];
        #pragma unroll
        for (int i = 0; i < 8; ++i) o2s[i] = o2v[r][i >> 1][i & 1];
        float m2 = o2s[0];
        #pragma unroll
        for (int i = 1; i < 8; ++i) m2 = fmaxf(m2, o2s[i]);
        v2f mm2; mm2[0]=m2; mm2[1]=m2;
        v2f se = (v2f)(0.f), de = (v2f)(0.f);
        #pragma unroll
        for (int p = 0; p < 4; ++p) {
            v2f a = o2v[r][p] - mm2;
            v2f e; e[0] = exp2_fast(a[0]); e[1] = exp2_fast(a[1]);
            se += e;
            v2f xp; xp[0]=xs[r][8+2*p]; xp[1]=xs[r][9+2*p];
            de += xp * e;
        }
        if (valid[r]) out[b0 + r * 256] = (de[0] + de[1]) * rcpf(se[0] + se[1]);
    }
}

extern "C" void kernel_launch(void* const* d_in, const int* in_sizes, int n_in,
                              void* d_out, int out_size, void* d_ws, size_t ws_size,
                              hipStream_t stream) {
    const float* x  = (const float*)d_in[0];
    const float* wq = (const float*)d_in[1];
    const float* wk = (const float*)d_in[2];
    const float* wv = (const float*)d_in[3];
    const float* Wh = (const float*)d_in[4];
    const float* bh = (const float*)d_in[5];
    const float* Wo = (const float*)d_in[6];
    const float* bo = (const float*)d_in[7];
    float* out = (float*)d_out;

    const int B = in_sizes[0] / 16;
    const int block = 256;
    const int rows_per_block = block * ROWS;
    const int grid = (B + rows_per_block - 1) / rows_per_block;
    fused_attn_mlp<<<grid, block, 0, stream>>>(x, wq, wk, wv, Wh, bh, Wo, bo, out, B);
}

// Round 4
// 127.118 us; speedup vs baseline: 1.4380x; 1.4380x over previous
//
#include <hip/hip_runtime.h>

// R11: full revert to R7 champion structure (54.2us) + two minimal trims.
// R10 post-mortem: hoisting 4 groups x 52 weight floats under unroll-4
// exceeded SGPR file (~208 needed vs ~100 free) -> compiler demoted the
// scalar weight path to per-lane VGPR broadcasts -> VALU busy-cycles 2.5x
// (36us-eq -> 91us-eq), dur 112us. No spill (WRITE stayed 2048). Lesson:
// never hold more than ~one group of weights live; R7's interleaved
// per-hh s_loads + unroll 2 is the verified optimum.
// Kept trims (local, couldn't have caused R10): (a) clamped-index x loads
// (no exec-mask load machinery; store still masked), (b) v1 deferred out
// of attn1 inner loop (-16 scalar muls, +8 pk muls per row).
// Ledger: occupancy lever dead (R9: 2x waves -> slower, VALUBusy down);
// spill cliff at VGPR<=44-needed (R8); SGPR cliff at ~1 group of weights
// (R10). Remaining structure is trans-bound: 866 trans/wave (784 exp2 +
// 82 rcp) ~ 65% of busy; exp count 392/row is algorithmically minimal.
// Kept: s_load weight path (no LDS, no barrier), exp2-domain softmax/
// sigmoid with per-row attained-max shift, Montgomery-batched sigmoid
// rcps, packed fp32 (v_pk_fma_f32), tree sums, x loads issued first.

typedef float v2f __attribute__((ext_vector_type(2)));

#define LOG2E 1.44269504088896340736f
#define ROWS 2

__device__ __forceinline__ float rcpf(float a) { return __builtin_amdgcn_rcpf(a); }

#if __has_builtin(__builtin_amdgcn_exp2f)
__device__ __forceinline__ float exp2_fast(float a) { return __builtin_amdgcn_exp2f(a); }
#else
__device__ __forceinline__ float exp2_fast(float a) { return __expf(0.6931471805599453f * a); }
#endif

__global__ __launch_bounds__(256, 4) void fused_attn_mlp(
    const float* __restrict__ x,
    const float* __restrict__ wq,
    const float* __restrict__ wk,
    const float* __restrict__ wv,
    const float* __restrict__ Wh,
    const float* __restrict__ bh,
    const float* __restrict__ Wo,
    const float* __restrict__ bo,
    float* __restrict__ out,
    int B)
{
    const int t = threadIdx.x;
    const int b0 = blockIdx.x * (256 * ROWS) + t;

    // Clamped indices: loads always in-bounds (no exec-mask machinery);
    // stores masked by valid[]. Correct for any B >= 1.
    bool valid[ROWS];
    int bidx[ROWS];
    #pragma unroll
    for (int r = 0; r < ROWS; ++r) {
        const int b = b0 + r * 256;
        valid[r] = b < B;
        bidx[r] = valid[r] ? b : (B - 1);
    }

    // ---- issue x loads first (VMEM latency hides under s_load setup) ----
    float4 xraw[ROWS][4];
    #pragma unroll
    for (int r = 0; r < ROWS; ++r) {
        const float4* xr = reinterpret_cast<const float4*>(x) + (size_t)bidx[r] * 4;
        xraw[r][0] = xr[0]; xraw[r][1] = xr[1]; xraw[r][2] = xr[2]; xraw[r][3] = xr[3];
    }

    // ---- unpack x rows ----
    float xs[ROWS][16];
    v2f xv2[ROWS][8];
    #pragma unroll
    for (int r = 0; r < ROWS; ++r) {
        xs[r][0]=xraw[r][0].x; xs[r][1]=xraw[r][0].y; xs[r][2]=xraw[r][0].z; xs[r][3]=xraw[r][0].w;
        xs[r][4]=xraw[r][1].x; xs[r][5]=xraw[r][1].y; xs[r][6]=xraw[r][1].z; xs[r][7]=xraw[r][1].w;
        xs[r][8]=xraw[r][2].x; xs[r][9]=xraw[r][2].y; xs[r][10]=xraw[r][2].z; xs[r][11]=xraw[r][2].w;
        xs[r][12]=xraw[r][3].x; xs[r][13]=xraw[r][3].y; xs[r][14]=xraw[r][3].z; xs[r][15]=xraw[r][3].w;
        #pragma unroll
        for (int p = 0; p < 8; ++p) { v2f v; v[0]=xs[r][2*p]; v[1]=xs[r][2*p+1]; xv2[r][p]=v; }
    }

    // ---- attention block 1 (D=16), exp2 domain ----
    const float kq1 = wk[0] * wq[0] * LOG2E;
    const float v1  = wv[0];

    float xmx[ROWS], xmn[ROWS];
    #pragma unroll
    for (int r = 0; r < ROWS; ++r) {
        float mx = xs[r][0], mn = xs[r][0];
        #pragma unroll
        for (int i = 1; i < 16; ++i) { mx = fmaxf(mx, xs[r][i]); mn = fminf(mn, xs[r][i]); }
        xmx[r] = mx; xmn[r] = mn;
    }

    v2f o1v[ROWS][8];
    #pragma unroll
    for (int r = 0; r < ROWS; ++r)
        #pragma unroll
        for (int p = 0; p < 8; ++p) o1v[r][p] = (v2f)(0.f);

    #pragma unroll
    for (int i = 0; i < 16; ++i) {
        v2f e2[ROWS][8];
        float w[ROWS];
        #pragma unroll
        for (int r = 0; r < ROWS; ++r) {
            const float c = kq1 * xs[r][i];
            const float m = fmaxf(c * xmx[r], c * xmn[r]);   // exact attained max -> args <= 0
            v2f cc; cc[0]=c; cc[1]=c;
            v2f mm; mm[0]=m; mm[1]=m;
            #pragma unroll
            for (int p = 0; p < 8; ++p) {
                v2f a = cc * xv2[r][p] - mm;                 // v_pk_fma_f32
                v2f e; e[0] = exp2_fast(a[0]); e[1] = exp2_fast(a[1]);
                e2[r][p] = e;
            }
            v2f s01 = e2[r][0] + e2[r][1];
            v2f s23 = e2[r][2] + e2[r][3];
            v2f s45 = e2[r][4] + e2[r][5];
            v2f s67 = e2[r][6] + e2[r][7];
            v2f sv  = (s01 + s23) + (s45 + s67);
            w[r] = xs[r][i] * rcpf(sv[0] + sv[1]);           // v1 deferred to epilogue
        }
        #pragma unroll
        for (int r = 0; r < ROWS; ++r) {
            v2f ww; ww[0]=w[r]; ww[1]=w[r];
            #pragma unroll
            for (int p = 0; p < 8; ++p) o1v[r][p] += ww * e2[r][p];
        }
    }

    // deferred v1 scale: one 8-pk pass per row instead of 16 in-loop muls
    {
        v2f v1v; v1v[0]=v1; v1v[1]=v1;
        #pragma unroll
        for (int r = 0; r < ROWS; ++r)
            #pragma unroll
            for (int p = 0; p < 8; ++p) o1v[r][p] *= v1v;
    }

    // ---- fused MLP: 16 -> 64 sigmoid -> 8. Weights read at UNIFORM global
    //      indices -> s_load (scalar pipe). R7 structure: per-hh inline
    //      loads, unroll 2. Sigmoid rcps Montgomery-batched. ----
    v2f x2v[ROWS][4];
    #pragma unroll
    for (int r = 0; r < ROWS; ++r)
        #pragma unroll
        for (int p = 0; p < 4; ++p) { v2f v; v[0]=bo[2*p]; v[1]=bo[2*p+1]; x2v[r][p]=v; }

    const v2f* Wh2 = reinterpret_cast<const v2f*>(Wh);   // [64][8] pairs

    #pragma unroll 2
    for (int g = 0; g < 16; ++g) {
        float apre[ROWS][4];
        #pragma unroll
        for (int hh = 0; hh < 4; ++hh) {
            const int h = g * 4 + hh;
            v2f whr[8];
            #pragma unroll
            for (int p = 0; p < 8; ++p) whr[p] = Wh2[h * 8 + p];   // uniform -> s_load
            const float bhh = bh[h];
            #pragma unroll
            for (int r = 0; r < ROWS; ++r) {
                v2f acc = whr[0] * o1v[r][0];
                #pragma unroll
                for (int p = 1; p < 8; ++p) acc += whr[p] * o1v[r][p];
                apre[r][hh] = acc[0] + acc[1] + bhh;
            }
        }
        float sg[ROWS][4];
        #pragma unroll
        for (int r = 0; r < ROWS; ++r) {
            // clamp inert for a > -20.8 (sigma < 1e-9 there); keeps
            // d = 1+2^la <= 1+2^30, so prod4 <= 2^121 (no overflow).
            float d[4];
            #pragma unroll
            for (int hh = 0; hh < 4; ++hh) {
                const float la = fminf(-apre[r][hh] * LOG2E, 30.f);
                d[hh] = 1.f + exp2_fast(la);
            }
            const float p01  = d[0] * d[1];
            const float p012 = p01 * d[2];
            const float rq   = rcpf(p012 * d[3]);
            const float i3 = rq * p012;
            const float tq = rq * d[3];      // 1/(d0 d1 d2)
            const float i2 = tq * p01;
            const float t2 = tq * d[2];      // 1/(d0 d1)
            sg[r][0] = t2 * d[1];
            sg[r][1] = t2 * d[0];
            sg[r][2] = i2;
            sg[r][3] = i3;
        }
        // x2[o] += Wo[o][h] * sg[h] for the 4 h's of this group; Wo accessed
        // at uniform indices (o compile-time, h unrolled) -> s_load.
        #pragma unroll
        for (int hh = 0; hh < 4; ++hh) {
            const int h = g * 4 + hh;
            #pragma unroll
            for (int p = 0; p < 4; ++p) {      // p = output pair (o = 2p, 2p+1)
                v2f wo2;
                wo2[0] = Wo[(2 * p) * 64 + h];       // uniform scalar loads
                wo2[1] = Wo[(2 * p + 1) * 64 + h];
                #pragma unroll
                for (int r = 0; r < ROWS; ++r) {
                    v2f sgv; sgv[0] = sg[r][hh]; sgv[1] = sg[r][hh];
                    x2v[r][p] += wo2 * sgv;
                }
            }
        }
    }

    // ---- attention block 2 (D=8), exp2 domain; LOG2E folded into o2 ----
    const float kq2 = wk[1] * wq[1] * LOG2E;
    const float v2s = wv[1] * LOG2E;

    float ys[ROWS][8];
    float ymx[ROWS], ymn[ROWS];
    #pragma unroll
    for (int r = 0; r < ROWS; ++r) {
        #pragma unroll
        for (int i = 0; i < 8; ++i) ys[r][i] = x2v[r][i >> 1][i & 1];
        float mx = ys[r][0], mn = ys[r][0];
        #pragma unroll
        for (int i = 1; i < 8; ++i) { mx = fmaxf(mx, ys[r][i]); mn = fminf(mn, ys[r][i]); }
        ymx[r] = mx; ymn[r] = mn;
    }

    v2f o2v[ROWS][4];
    #pragma unroll
    for (int r = 0; r < ROWS; ++r)
        #pragma unroll
        for (int p = 0; p < 4; ++p) o2v[r][p] = (v2f)(0.f);

    #pragma unroll
    for (int i = 0; i < 8; ++i) {
        v2f e2[ROWS][4];
        float w[ROWS];
        #pragma unroll
        for (int r = 0; r < ROWS; ++r) {
            const float c = kq2 * ys[r][i];
            const float m = fmaxf(c * ymx[r], c * ymn[r]);
            v2f cc; cc[0]=c; cc[1]=c;
            v2f mm; mm[0]=m; mm[1]=m;
            #pragma unroll
            for (int p = 0; p < 4; ++p) {
                v2f a = cc * x2v[r][p] - mm;
                v2f e; e[0] = exp2_fast(a[0]); e[1] = exp2_fast(a[1]);
                e2[r][p] = e;
            }
            v2f sv = (e2[r][0] + e2[r][1]) + (e2[r][2] + e2[r][3]);
            w[r] = v2s * ys[r][i] * rcpf(sv[0] + sv[1]);
        }
        #pragma unroll
        for (int r = 0; r < ROWS; ++r) {
            v2f ww; ww[0]=w[r]; ww[1]=w[r];
            #pragma unroll
            for (int p = 0; p < 4; ++p) o2v[r][p] += ww * e2[r][p];
        }
    }

    // ---- final softmax (log2 domain) + dot with x[8:16] ----
    #pragma unroll
    for (int r = 0; r < ROWS; ++r) {
        float o2s[8];
        #pragma unroll
        for (int i = 0; i < 8; ++i) o2s[i] = o2v[r][i >> 1][i & 1];
        float m2 = o2s[0];
        #pragma unroll
        for (int i = 1; i < 8; ++i) m2 = fmaxf(m2, o2s[i]);
        v2f mm2; mm2[0]=m2; mm2[1]=m2;
        v2f se = (v2f)(0.f), de = (v2f)(0.f);
        #pragma unroll
        for (int p = 0; p < 4; ++p) {
            v2f a = o2v[r][p] - mm2;
            v2f e; e[0] = exp2_fast(a[0]); e[1] = exp2_fast(a[1]);
            se += e;
            v2f xp; xp[0]=xs[r][8+2*p]; xp[1]=xs[r][9+2*p];
            de += xp * e;
        }
        if (valid[r]) out[b0 + r * 256] = (de[0] + de[1]) * rcpf(se[0] + se[1]);
    }
}

extern "C" void kernel_launch(void* const* d_in, const int* in_sizes, int n_in,
                              void* d_out, int out_size, void* d_ws, size_t ws_size,
                              hipStream_t stream) {
    const float* x  = (const float*)d_in[0];
    const float* wq = (const float*)d_in[1];
    const float* wk = (const float*)d_in[2];
    const float* wv = (const float*)d_in[3];
    const float* Wh = (const float*)d_in[4];
    const float* bh = (const float*)d_in[5];
    const float* Wo = (const float*)d_in[6];
    const float* bo = (const float*)d_in[7];
    float* out = (float*)d_out;

    const int B = in_sizes[0] / 16;
    const int block = 256;
    const int rows_per_block = block * ROWS;
    const int grid = (B + rows_per_block - 1) / rows_per_block;
    fused_attn_mlp<<<grid, block, 0, stream>>>(x, wq, wk, wv, Wh, bh, Wo, bo, out, B);
}